// Round 3
// baseline (660.635 us; speedup 1.0000x reference)
//
#include <hip/hip_runtime.h>
#include <cstdint>
#include <cstddef>

// Problem constants (fixed by reference).
#define BATCH 16
#define SEQ   4096
#define NS    512
#define TLAG  96             // truncation: ||A^96|| ~ 4e-5 (tail ~1e-3) << bf16 noise 0.08
#define CTILE 256            // conv time-rows per block; grid 16x16 = 256 blocks = 1/CU
#define XROWS (CTILE + TLAG - 1)   // 351 staged rows
#define XSTR  72             // LDS row stride in u16 (144 B, 16B-aligned)

typedef unsigned short u16;
typedef unsigned int   u32;
typedef short bf16x8 __attribute__((ext_vector_type(8)));   // 8 bf16 = 4 VGPRs
typedef float f32x4  __attribute__((ext_vector_type(4)));   // MFMA accumulator

__device__ __forceinline__ u16 f2bf(float f) {
    u32 u = __builtin_bit_cast(u32, f);
    return (u16)((u + 0x7FFFu + ((u >> 16) & 1u)) >> 16);   // RNE
}
__device__ __forceinline__ float bf2f(u16 h) {
    return __builtin_bit_cast(float, (u32)h << 16);
}

// ---------------------------------------------------------------------------
// Grid-wide barrier (persistent precompute kernel, 256 blocks = 1/CU, all
// co-resident). cnt at bar[0], generation at bar[32] (separate cachelines).
// Device-scope atomics + __threadfence for cross-XCD visibility.
// ---------------------------------------------------------------------------
__device__ __forceinline__ void grid_sync(int* bar, int nblk) {
    __threadfence();
    __syncthreads();
    if (threadIdx.x == 0) {
        int g = __hip_atomic_load(bar + 32, __ATOMIC_RELAXED, __HIP_MEMORY_SCOPE_AGENT);
        int a = __hip_atomic_fetch_add(bar, 1, __ATOMIC_ACQ_REL, __HIP_MEMORY_SCOPE_AGENT);
        if (a == nblk - 1) {
            __hip_atomic_store(bar, 0, __ATOMIC_RELAXED, __HIP_MEMORY_SCOPE_AGENT);
            __hip_atomic_store(bar + 32, g + 1, __ATOMIC_RELEASE, __HIP_MEMORY_SCOPE_AGENT);
        } else {
            while (__hip_atomic_load(bar + 32, __ATOMIC_ACQUIRE, __HIP_MEMORY_SCOPE_AGENT) == g)
                __builtin_amdgcn_s_sleep(2);
        }
    }
    __syncthreads();
}

// ---------------------------------------------------------------------------
// gemm_tile64: one 64x64 output tile, K=512, bf16 in / fp32 acc / bf16 out.
// bT is the B-operand stored transposed ([Ntot][512]); n0 = 64-col slice.
// Optional row-major out (oRM pre-row-offset) and transposed out (oT, abs
// row rowT). 256 threads = 4 waves x 16 rows. Layouts verified rounds 1-2.
// ---------------------------------------------------------------------------
__device__ __forceinline__ void gemm_tile64(const u16* __restrict__ apM, int lda,
                                            const u16* __restrict__ bT, int ldbt, int n0,
                                            u16* __restrict__ oRM, int ldo,
                                            u16* __restrict__ oT, int ldoT, int rowT)
{
    const int tid = threadIdx.x;
    const int w = tid >> 6, l = tid & 63;
    const int lr = l & 15, q8 = (l >> 4) * 8;

    const u16* ap  = apM + (size_t)(w * 16 + lr) * lda + q8;
    const u16* bp0 = bT  + (size_t)(n0 + lr) * ldbt + q8;

    f32x4 acc[4];
    const f32x4 zero = {0.f, 0.f, 0.f, 0.f};
    #pragma unroll
    for (int nt = 0; nt < 4; ++nt) acc[nt] = zero;

    #pragma unroll 4
    for (int ks = 0; ks < 16; ++ks) {
        const bf16x8 a = *(const bf16x8*)(ap + ks * 32);
        #pragma unroll
        for (int nt = 0; nt < 4; ++nt) {
            const bf16x8 bfr = *(const bf16x8*)(bp0 + (size_t)nt * 16 * ldbt + ks * 32);
            acc[nt] = __builtin_amdgcn_mfma_f32_16x16x32_bf16(a, bfr, acc[nt], 0, 0, 0);
        }
    }

    const int rr = (l >> 4) * 4;    // C/D: row=(lane>>4)*4+reg, col=lane&15
    #pragma unroll
    for (int nt = 0; nt < 4; ++nt) {
        const int col = n0 + nt * 16 + lr;
        if (oRM) {
            #pragma unroll
            for (int r = 0; r < 4; ++r)
                oRM[(size_t)(w * 16 + rr + r) * ldo + col] = f2bf(acc[nt][r]);
        }
        if (oT) {
            ushort4 pk;
            pk.x = f2bf(acc[nt][0]); pk.y = f2bf(acc[nt][1]);
            pk.z = f2bf(acc[nt][2]); pk.w = f2bf(acc[nt][3]);
            *(ushort4*)(oT + (size_t)col * ldoT + rowT + w * 16 + rr) = pk;
        }
    }
}

// Same GEMM but N=64 only, epilogue to LDS (row-major, stride XSTR).
__device__ __forceinline__ void gemm_tile64_lds(const u16* __restrict__ apM, int lda,
                                                const u16* __restrict__ bT, int ldbt,
                                                u16* ldsOut)
{
    const int tid = threadIdx.x;
    const int w = tid >> 6, l = tid & 63;
    const int lr = l & 15, q8 = (l >> 4) * 8;

    const u16* ap  = apM + (size_t)(w * 16 + lr) * lda + q8;
    const u16* bp0 = bT  + (size_t)lr * ldbt + q8;

    f32x4 acc[4];
    const f32x4 zero = {0.f, 0.f, 0.f, 0.f};
    #pragma unroll
    for (int nt = 0; nt < 4; ++nt) acc[nt] = zero;

    #pragma unroll 4
    for (int ks = 0; ks < 16; ++ks) {
        const bf16x8 a = *(const bf16x8*)(ap + ks * 32);
        #pragma unroll
        for (int nt = 0; nt < 4; ++nt) {
            const bf16x8 bfr = *(const bf16x8*)(bp0 + (size_t)nt * 16 * ldbt + ks * 32);
            acc[nt] = __builtin_amdgcn_mfma_f32_16x16x32_bf16(a, bfr, acc[nt], 0, 0, 0);
        }
    }

    const int rr = (l >> 4) * 4;
    #pragma unroll
    for (int nt = 0; nt < 4; ++nt) {
        const int col = nt * 16 + lr;
        #pragma unroll
        for (int r = 0; r < 4; ++r)
            ldsOut[(w * 16 + rr + r) * XSTR + col] = f2bf(acc[nt][r]);
    }
}

// ---------------------------------------------------------------------------
// precompute: ONE persistent kernel (256 blocks x 256 thr, grid barriers)
// replacing round-2's 9-launch chain (~177 us of launch/dependency cost).
//  P0: A->Ap0/ApT0, B->BT, C->W_0 (bf16).
//  P1..P7: W-chain doubling levels h=1..64 (expansion + squaring fused).
//  P8: G_m = W_m @ B -> LDS -> swizzle to B-fragment order (D folded at m=0).
// ---------------------------------------------------------------------------
__global__ __launch_bounds__(256, 1) void precompute(
    const float* __restrict__ A, const float* __restrict__ B,
    const float* __restrict__ C, const float* __restrict__ D,
    u16* __restrict__ Ap0, u16* __restrict__ Ap1,
    u16* __restrict__ ApT0, u16* __restrict__ ApT1,
    u16* __restrict__ BT, u16* __restrict__ Wall, u16* __restrict__ Gsw,
    int* __restrict__ bar)
{
    __shared__ u16 Gt[64 * XSTR];   // 9 KB, final phase only
    const int tid = threadIdx.x;
    const int gid = blockIdx.x * 256 + tid;   // 65536 threads

    // ---- P0: conversions ----
    {   // A: 512x512 = 65536 float4, one per thread; RM + transposed
        const float4 v = ((const float4*)A)[gid];
        const int base = gid * 4, r = base >> 9, c = base & 511;
        ushort4 o; o.x = f2bf(v.x); o.y = f2bf(v.y); o.z = f2bf(v.z); o.w = f2bf(v.w);
        *(ushort4*)(Ap0 + base) = o;
        ApT0[(size_t)(c + 0) * 512 + r] = o.x;
        ApT0[(size_t)(c + 1) * 512 + r] = o.y;
        ApT0[(size_t)(c + 2) * 512 + r] = o.z;
        ApT0[(size_t)(c + 3) * 512 + r] = o.w;
    }
    if (gid < 8192) {   // B: 512x64 -> BT[i][k]
        const float4 v = ((const float4*)B)[gid];
        const int base = gid * 4, k = base >> 6, c = base & 63;
        BT[(size_t)(c + 0) * 512 + k] = f2bf(v.x);
        BT[(size_t)(c + 1) * 512 + k] = f2bf(v.y);
        BT[(size_t)(c + 2) * 512 + k] = f2bf(v.z);
        BT[(size_t)(c + 3) * 512 + k] = f2bf(v.w);
        // C: 64x512 -> W_0 straight copy (also 8192 float4)
        const float4 vc = ((const float4*)C)[gid];
        ushort4 oc; oc.x = f2bf(vc.x); oc.y = f2bf(vc.y); oc.z = f2bf(vc.z); oc.w = f2bf(vc.w);
        *(ushort4*)(Wall + gid * 4) = oc;
    }
    grid_sync(bar, 256);

    // ---- levels: h = 1,2,4,8,16,32,64 ----
    int h = 1, pp = 0;
    while (h < TLAG) {
        const int nexp  = (h < TLAG - h) ? h : (TLAG - h);
        const int do_sq = (2 * h <= 64) ? 1 : 0;
        const u16* apc  = pp ? Ap1 : Ap0;
        const u16* aptc = pp ? ApT1 : ApT0;
        u16* apn  = pp ? Ap0 : Ap1;
        u16* aptn = pp ? ApT0 : ApT1;
        const int ntiles = nexp * 8 + (do_sq ? 64 : 0);
        for (int t = blockIdx.x; t < ntiles; t += 256) {
            if (t < nexp * 8) {           // W[h+j] = W[j] @ A^h
                const int j = t >> 3, n0 = (t & 7) * 64;
                gemm_tile64(Wall + (size_t)j * 64 * NS, NS, aptc, NS, n0,
                            Wall + (size_t)(h + j) * 64 * NS, NS, nullptr, NS, 0);
            } else {                       // A^{2h} = A^h @ A^h (RM + T)
                const int t2 = t - nexp * 8, j = t2 >> 3, n0 = (t2 & 7) * 64;
                gemm_tile64(apc + (size_t)j * 64 * NS, NS, aptc, NS, n0,
                            apn + (size_t)j * 64 * NS, NS, aptn, NS, j * 64);
            }
        }
        grid_sync(bar, 256);
        if (do_sq) pp ^= 1;
        h += nexp;
    }

    // ---- final: G_m = W_m @ B, swizzle to conv B-fragment order ----
    for (int m = blockIdx.x; m < TLAG; m += 256) {   // 96 active blocks
        gemm_tile64_lds(Wall + (size_t)m * 64 * NS, NS, BT, NS, Gt);
        __syncthreads();
        for (int u = tid; u < 512; u += 256) {
            const int f = u >> 6, l = u & 63;
            const int nt = f & 3, ks = f >> 2;
            const int o  = nt * 16 + (l & 15);
            const int i0 = ks * 32 + (l >> 4) * 8;
            u16 v[8];
            #pragma unroll
            for (int j = 0; j < 8; ++j) {
                u16 g = Gt[o * XSTR + i0 + j];
                if (m == 0) g = f2bf(bf2f(g) + D[o * 64 + i0 + j]);   // fold D into lag 0
                v[j] = g;
            }
            ushort4* dst = (ushort4*)(Gsw + ((size_t)(m * 8 + f) * 64 + l) * 8);
            ushort4 p0, p1;
            p0.x = v[0]; p0.y = v[1]; p0.z = v[2]; p0.w = v[3];
            p1.x = v[4]; p1.y = v[5]; p1.z = v[6]; p1.w = v[7];
            dst[0] = p0; dst[1] = p1;
        }
        __syncthreads();
    }
}

// ---------------------------------------------------------------------------
// conv step: one lag m. X A-frags from LDS, G B-frags from registers.
// ---------------------------------------------------------------------------
__device__ __forceinline__ void conv_step(const u16* xs, const uint4* bn,
                                          int pbase, int q8, f32x4 acc[4][4])
{
    bf16x8 a[4][2];
    #pragma unroll
    for (int mt = 0; mt < 4; ++mt)
        #pragma unroll
        for (int ks = 0; ks < 2; ++ks)
            a[mt][ks] = *(const bf16x8*)(xs + (pbase + mt * 16) * XSTR + ks * 32 + q8);
    #pragma unroll
    for (int ks = 0; ks < 2; ++ks)
        #pragma unroll
        for (int mt = 0; mt < 4; ++mt)
            #pragma unroll
            for (int nt = 0; nt < 4; ++nt)
                acc[mt][nt] = __builtin_amdgcn_mfma_f32_16x16x32_bf16(
                    a[mt][ks], __builtin_bit_cast(bf16x8, bn[ks * 4 + nt]), acc[mt][nt], 0, 0, 0);
}

// ---------------------------------------------------------------------------
// conv_kernel: y[b,t,o] = sum_{m<96} sum_i G_m[o][i] x[b][t-m][i]
// Grid (16,16) = 256 blocks (1/CU); 4 waves x R=64 rows (halves per-flop G
// traffic vs round 2's R=32 — the measured bottleneck). X staged fp32->bf16
// directly (xbf pass deleted). G: even/odd register double-buffer (no v_mov
// repack), __syncthreads every 8 lags keeps waves lockstep for L1 G-reuse.
// ---------------------------------------------------------------------------
__global__ __launch_bounds__(256, 1) void conv_kernel(const float* __restrict__ x,
                                                      const u16* __restrict__ gsw,
                                                      float* __restrict__ y)
{
    __shared__ u16 Xs[XROWS * XSTR];   // 50,544 B

    const int tid = threadIdx.x;
    const int b  = blockIdx.y;
    const int t0 = blockIdx.x * CTILE;

    // Stage rows p=0..350 (= times t0-95 .. t0+255; t<0 -> zeros), converting.
    for (int u = tid; u < XROWS * 16; u += 256) {
        const int p = u >> 4, g = u & 15;
        const int t = t0 - (TLAG - 1) + p;
        ushort4 o;
        if (t < 0) { o.x = 0; o.y = 0; o.z = 0; o.w = 0; }
        else {
            const float4 v = *(const float4*)(x + ((size_t)b * SEQ + t) * 64 + g * 4);
            o.x = f2bf(v.x); o.y = f2bf(v.y); o.z = f2bf(v.z); o.w = f2bf(v.w);
        }
        *(ushort4*)&Xs[p * XSTR + g * 4] = o;
    }
    __syncthreads();

    const int w  = tid >> 6, l = tid & 63;
    const int lr = l & 15, q8 = (l >> 4) * 8;
    const int wrow = w * 64;

    const uint4* g4 = (const uint4*)gsw + l;

    f32x4 acc[4][4];
    const f32x4 zero = {0.f, 0.f, 0.f, 0.f};
    #pragma unroll
    for (int mt = 0; mt < 4; ++mt)
        #pragma unroll
        for (int nt = 0; nt < 4; ++nt) acc[mt][nt] = zero;

    uint4 bn0[8], bn1[8];
    #pragma unroll
    for (int f = 0; f < 8; ++f) bn0[f] = g4[f * 64];

    for (int m = 0; m < TLAG; m += 2) {
        {   // prefetch m+1 (always valid: TLAG even)
            const uint4* gp = g4 + (size_t)(m + 1) * 512;
            #pragma unroll
            for (int f = 0; f < 8; ++f) bn1[f] = gp[f * 64];
        }
        conv_step(Xs, bn0, wrow + lr + (TLAG - 1) - m, q8, acc);
        {   // prefetch m+2 (clamped; duplicate read is harmless)
            const int mp = (m + 2 < TLAG) ? (m + 2) : (TLAG - 1);
            const uint4* gp = g4 + (size_t)mp * 512;
            #pragma unroll
            for (int f = 0; f < 8; ++f) bn0[f] = gp[f * 64];
        }
        conv_step(Xs, bn1, wrow + lr + (TLAG - 1) - (m + 1), q8, acc);
        if ((m & 7) == 6) __syncthreads();   // bound wave drift -> L1 G hits
    }

    // Epilogue: col=lane&15 (o), row=(lane>>4)*4+reg (time).
    const int rr = (l >> 4) * 4;
    #pragma unroll
    for (int mt = 0; mt < 4; ++mt) {
        #pragma unroll
        for (int nt = 0; nt < 4; ++nt) {
            const int t = t0 + wrow + mt * 16 + rr;
            const int o = nt * 16 + lr;
            float* yp = y + ((size_t)b * SEQ + t) * 64 + o;
            #pragma unroll
            for (int r = 0; r < 4; ++r) yp[(size_t)r * 64] = acc[mt][nt][r];
        }
    }
}

// ---------------------------------------------------------------------------
// Workspace layout (bytes):
//   0        bar      512   (grid-barrier cnt/gen; zeroed via hipMemsetAsync)
//   512      Ap0   524288   (A^h row-major, ping)
//   524800   Ap1   524288   (pong)
//   1049088  ApT0  524288   (A^h transposed, ping)
//   1573376  ApT1  524288   (pong)
//   2097664  BT     65536   (B^T [64][512])
//   2163200  Wall 6291456   ([96*64][512]: row m*64+o = (C A^m)[o][:])
//   8454656  Gsw   786432   (B-fragment-swizzled conv kernels, 96 lags)
//   total 9,241,088
// ---------------------------------------------------------------------------
extern "C" void kernel_launch(void* const* d_in, const int* in_sizes, int n_in,
                              void* d_out, int out_size, void* d_ws, size_t ws_size,
                              hipStream_t stream)
{
    const float* x = (const float*)d_in[0];
    const float* A = (const float*)d_in[1];
    const float* B = (const float*)d_in[2];
    const float* C = (const float*)d_in[3];
    const float* D = (const float*)d_in[4];
    float* y = (float*)d_out;

    char* w = (char*)d_ws;
    int* bar  = (int*)(w + 0);
    u16* Ap0  = (u16*)(w + 512);
    u16* Ap1  = (u16*)(w + 524800);
    u16* ApT0 = (u16*)(w + 1049088);
    u16* ApT1 = (u16*)(w + 1573376);
    u16* BT   = (u16*)(w + 2097664);
    u16* Wall = (u16*)(w + 2163200);
    u16* Gsw  = (u16*)(w + 8454656);

    hipMemsetAsync(bar, 0, 512, stream);
    precompute<<<256, 256, 0, stream>>>(A, B, C, D, Ap0, Ap1, ApT0, ApT1,
                                        BT, Wall, Gsw, bar);
    conv_kernel<<<dim3(SEQ / CTILE, BATCH), 256, 0, stream>>>(x, Gsw, y);
}

// Round 4
// 321.234 us; speedup vs baseline: 2.0566x; 2.0566x over previous
//
#include <hip/hip_runtime.h>
#include <cstdint>
#include <cstddef>

// Problem constants (fixed by reference).
#define BATCH 16
#define SEQ   4096
#define NS    512
#define TLAG  96             // truncation: ||A^96|| ~ 4e-5 -> tail << bf16 noise 0.078
#define CTILE 256            // conv time-rows per block; grid 16x16 = 256 blocks = 1/CU
#define XROWS (CTILE + TLAG - 1)   // 351 staged rows
#define XSTR  72             // LDS row stride in u16 (144 B, 16B-aligned)

typedef unsigned short u16;
typedef unsigned int   u32;
typedef short bf16x8 __attribute__((ext_vector_type(8)));   // 8 bf16 = 4 VGPRs
typedef float f32x4  __attribute__((ext_vector_type(4)));   // MFMA accumulator

__device__ __forceinline__ u16 f2bf(float f) {
    u32 u = __builtin_bit_cast(u32, f);
    return (u16)((u + 0x7FFFu + ((u >> 16) & 1u)) >> 16);   // RNE
}
__device__ __forceinline__ float bf2f(u16 h) {
    return __builtin_bit_cast(float, (u32)h << 16);
}

// ---------------------------------------------------------------------------
// Grid-wide barrier, 256 co-resident blocks. ROUND-3 FIX: the poll loop uses
// RELAXED atomic loads (no per-iteration cache invalidate — that was the
// 65 us/barrier pathology). Exactly one release fence before arrival (flush
// this block's writes to device scope) and one acquire fence on exit
// (invalidate stale lines once). gen store is RELEASE so the counter reset
// is ordered before it.
// ---------------------------------------------------------------------------
__device__ __forceinline__ void grid_sync(int* bar, int nblk) {
    __syncthreads();   // includes s_waitcnt vmcnt(0): block's stores are in L2
    if (threadIdx.x == 0) {
        __builtin_amdgcn_fence(__ATOMIC_RELEASE, "agent");   // wb to device scope
        const int g = __hip_atomic_load(bar + 32, __ATOMIC_RELAXED, __HIP_MEMORY_SCOPE_AGENT);
        const int a = __hip_atomic_fetch_add(bar, 1, __ATOMIC_RELAXED, __HIP_MEMORY_SCOPE_AGENT);
        if (a == nblk - 1) {
            __hip_atomic_store(bar, 0, __ATOMIC_RELAXED, __HIP_MEMORY_SCOPE_AGENT);
            __hip_atomic_store(bar + 32, g + 1, __ATOMIC_RELEASE, __HIP_MEMORY_SCOPE_AGENT);
        } else {
            while (__hip_atomic_load(bar + 32, __ATOMIC_RELAXED, __HIP_MEMORY_SCOPE_AGENT) == g)
                __builtin_amdgcn_s_sleep(4);
        }
        __builtin_amdgcn_fence(__ATOMIC_ACQUIRE, "agent");   // one invalidate on exit
    }
    __syncthreads();
}

// ---------------------------------------------------------------------------
// gemm_tile64: one 64x64 output tile, K=512, bf16 in / fp32 acc / bf16 out.
// bT is the B-operand stored transposed ([Ntot][512]); n0 = 64-col slice.
// Optional row-major out (oRM pre-row-offset) and transposed out (oT, abs
// row rowT). 256 threads = 4 waves x 16 rows. Layouts verified rounds 1-3.
// ---------------------------------------------------------------------------
__device__ __forceinline__ void gemm_tile64(const u16* __restrict__ apM, int lda,
                                            const u16* __restrict__ bT, int ldbt, int n0,
                                            u16* __restrict__ oRM, int ldo,
                                            u16* __restrict__ oT, int ldoT, int rowT)
{
    const int tid = threadIdx.x;
    const int w = tid >> 6, l = tid & 63;
    const int lr = l & 15, q8 = (l >> 4) * 8;

    const u16* ap  = apM + (size_t)(w * 16 + lr) * lda + q8;
    const u16* bp0 = bT  + (size_t)(n0 + lr) * ldbt + q8;

    f32x4 acc[4];
    const f32x4 zero = {0.f, 0.f, 0.f, 0.f};
    #pragma unroll
    for (int nt = 0; nt < 4; ++nt) acc[nt] = zero;

    #pragma unroll 4
    for (int ks = 0; ks < 16; ++ks) {
        const bf16x8 a = *(const bf16x8*)(ap + ks * 32);
        #pragma unroll
        for (int nt = 0; nt < 4; ++nt) {
            const bf16x8 bfr = *(const bf16x8*)(bp0 + (size_t)nt * 16 * ldbt + ks * 32);
            acc[nt] = __builtin_amdgcn_mfma_f32_16x16x32_bf16(a, bfr, acc[nt], 0, 0, 0);
        }
    }

    const int rr = (l >> 4) * 4;    // C/D: row=(lane>>4)*4+reg, col=lane&15
    #pragma unroll
    for (int nt = 0; nt < 4; ++nt) {
        const int col = n0 + nt * 16 + lr;
        if (oRM) {
            #pragma unroll
            for (int r = 0; r < 4; ++r)
                oRM[(size_t)(w * 16 + rr + r) * ldo + col] = f2bf(acc[nt][r]);
        }
        if (oT) {
            ushort4 pk;
            pk.x = f2bf(acc[nt][0]); pk.y = f2bf(acc[nt][1]);
            pk.z = f2bf(acc[nt][2]); pk.w = f2bf(acc[nt][3]);
            *(ushort4*)(oT + (size_t)col * ldoT + rowT + w * 16 + rr) = pk;
        }
    }
}

// Same GEMM, N=64 only, epilogue to LDS (row-major, stride XSTR).
__device__ __forceinline__ void gemm_tile64_lds(const u16* __restrict__ apM, int lda,
                                                const u16* __restrict__ bT, int ldbt,
                                                u16* ldsOut)
{
    const int tid = threadIdx.x;
    const int w = tid >> 6, l = tid & 63;
    const int lr = l & 15, q8 = (l >> 4) * 8;

    const u16* ap  = apM + (size_t)(w * 16 + lr) * lda + q8;
    const u16* bp0 = bT  + (size_t)lr * ldbt + q8;

    f32x4 acc[4];
    const f32x4 zero = {0.f, 0.f, 0.f, 0.f};
    #pragma unroll
    for (int nt = 0; nt < 4; ++nt) acc[nt] = zero;

    #pragma unroll 4
    for (int ks = 0; ks < 16; ++ks) {
        const bf16x8 a = *(const bf16x8*)(ap + ks * 32);
        #pragma unroll
        for (int nt = 0; nt < 4; ++nt) {
            const bf16x8 bfr = *(const bf16x8*)(bp0 + (size_t)nt * 16 * ldbt + ks * 32);
            acc[nt] = __builtin_amdgcn_mfma_f32_16x16x32_bf16(a, bfr, acc[nt], 0, 0, 0);
        }
    }

    const int rr = (l >> 4) * 4;
    #pragma unroll
    for (int nt = 0; nt < 4; ++nt) {
        const int col = nt * 16 + lr;
        #pragma unroll
        for (int r = 0; r < 4; ++r)
            ldsOut[(w * 16 + rr + r) * XSTR + col] = f2bf(acc[nt][r]);
    }
}

// ---------------------------------------------------------------------------
// precompute: ONE persistent kernel (256 blocks, 8 cheap grid barriers).
//  P0: A->Ap0/ApT0, B->BT, C->W_0 (bf16).
//  L1..L7: W-chain doubling h=1,2,4,8,16,32,64 (expansion + squaring fused).
//  final: G_m = W_m @ B -> LDS -> swizzle to conv B-fragment order (D folded
//  into lag 0).
// ---------------------------------------------------------------------------
__global__ __launch_bounds__(256, 1) void precompute(
    const float* __restrict__ A, const float* __restrict__ B,
    const float* __restrict__ C, const float* __restrict__ D,
    u16* __restrict__ Ap0, u16* __restrict__ Ap1,
    u16* __restrict__ ApT0, u16* __restrict__ ApT1,
    u16* __restrict__ BT, u16* __restrict__ Wall, u16* __restrict__ Gsw,
    int* __restrict__ bar)
{
    __shared__ u16 Gt[64 * XSTR];   // 9 KB, final phase only
    const int tid = threadIdx.x;
    const int gid = blockIdx.x * 256 + tid;   // 65536 threads

    // ---- P0: conversions ----
    {   // A: 512x512 = 65536 float4, one per thread; RM + transposed
        const float4 v = ((const float4*)A)[gid];
        const int base = gid * 4, r = base >> 9, c = base & 511;
        ushort4 o; o.x = f2bf(v.x); o.y = f2bf(v.y); o.z = f2bf(v.z); o.w = f2bf(v.w);
        *(ushort4*)(Ap0 + base) = o;
        ApT0[(size_t)(c + 0) * 512 + r] = o.x;
        ApT0[(size_t)(c + 1) * 512 + r] = o.y;
        ApT0[(size_t)(c + 2) * 512 + r] = o.z;
        ApT0[(size_t)(c + 3) * 512 + r] = o.w;
    }
    if (gid < 8192) {   // B: 512x64 -> BT[i][k]
        const float4 v = ((const float4*)B)[gid];
        const int base = gid * 4, k = base >> 6, c = base & 63;
        BT[(size_t)(c + 0) * 512 + k] = f2bf(v.x);
        BT[(size_t)(c + 1) * 512 + k] = f2bf(v.y);
        BT[(size_t)(c + 2) * 512 + k] = f2bf(v.z);
        BT[(size_t)(c + 3) * 512 + k] = f2bf(v.w);
        // C: 64x512 -> W_0 straight copy (also 8192 float4)
        const float4 vc = ((const float4*)C)[gid];
        ushort4 oc; oc.x = f2bf(vc.x); oc.y = f2bf(vc.y); oc.z = f2bf(vc.z); oc.w = f2bf(vc.w);
        *(ushort4*)(Wall + gid * 4) = oc;
    }
    grid_sync(bar, 256);

    // ---- levels: h = 1,2,4,8,16,32,64 ----
    int h = 1, pp = 0;
    while (h < TLAG) {
        const int nexp  = (h < TLAG - h) ? h : (TLAG - h);
        const int do_sq = (2 * h <= 64) ? 1 : 0;
        const u16* apc  = pp ? Ap1 : Ap0;
        const u16* aptc = pp ? ApT1 : ApT0;
        u16* apn  = pp ? Ap0 : Ap1;
        u16* aptn = pp ? ApT0 : ApT1;
        const int ntiles = nexp * 8 + (do_sq ? 64 : 0);
        for (int t = blockIdx.x; t < ntiles; t += 256) {
            if (t < nexp * 8) {           // W[h+j] = W[j] @ A^h
                const int j = t >> 3, n0 = (t & 7) * 64;
                gemm_tile64(Wall + (size_t)j * 64 * NS, NS, aptc, NS, n0,
                            Wall + (size_t)(h + j) * 64 * NS, NS, nullptr, NS, 0);
            } else {                       // A^{2h} = A^h @ A^h (RM + T)
                const int t2 = t - nexp * 8, j = t2 >> 3, n0 = (t2 & 7) * 64;
                gemm_tile64(apc + (size_t)j * 64 * NS, NS, aptc, NS, n0,
                            apn + (size_t)j * 64 * NS, NS, aptn, NS, j * 64);
            }
        }
        grid_sync(bar, 256);
        if (do_sq) pp ^= 1;
        h += nexp;
    }

    // ---- final: G_m = W_m @ B, swizzle to conv B-fragment order ----
    for (int m = blockIdx.x; m < TLAG; m += 256) {   // blocks 0..95 active
        gemm_tile64_lds(Wall + (size_t)m * 64 * NS, NS, BT, NS, Gt);
        __syncthreads();
        for (int u = tid; u < 512; u += 256) {
            const int f = u >> 6, l = u & 63;
            const int nt = f & 3, ks = f >> 2;
            const int o  = nt * 16 + (l & 15);
            const int i0 = ks * 32 + (l >> 4) * 8;
            u16 v[8];
            #pragma unroll
            for (int j = 0; j < 8; ++j) {
                u16 g = Gt[o * XSTR + i0 + j];
                if (m == 0) g = f2bf(bf2f(g) + D[o * 64 + i0 + j]);   // fold D into lag 0
                v[j] = g;
            }
            ushort4* dst = (ushort4*)(Gsw + ((size_t)(m * 8 + f) * 64 + l) * 8);
            ushort4 p0, p1;
            p0.x = v[0]; p0.y = v[1]; p0.z = v[2]; p0.w = v[3];
            p1.x = v[4]; p1.y = v[5]; p1.z = v[6]; p1.w = v[7];
            dst[0] = p0; dst[1] = p1;
        }
        __syncthreads();
    }
}

// ---------------------------------------------------------------------------
// conv step: one lag m. X A-frags from LDS, G B-frags from registers.
// ---------------------------------------------------------------------------
__device__ __forceinline__ void conv_step(const u16* xs, const uint4* bn,
                                          int pbase, int q8, f32x4 acc[4][4])
{
    bf16x8 a[4][2];
    #pragma unroll
    for (int mt = 0; mt < 4; ++mt)
        #pragma unroll
        for (int ks = 0; ks < 2; ++ks)
            a[mt][ks] = *(const bf16x8*)(xs + (pbase + mt * 16) * XSTR + ks * 32 + q8);
    #pragma unroll
    for (int ks = 0; ks < 2; ++ks)
        #pragma unroll
        for (int mt = 0; mt < 4; ++mt)
            #pragma unroll
            for (int nt = 0; nt < 4; ++nt)
                acc[mt][nt] = __builtin_amdgcn_mfma_f32_16x16x32_bf16(
                    a[mt][ks], __builtin_bit_cast(bf16x8, bn[ks * 4 + nt]), acc[mt][nt], 0, 0, 0);
}

// ---------------------------------------------------------------------------
// conv_kernel: y[b,t,o] = sum_{m<96} sum_i G_m[o][i] x[b][t-m][i]
// Grid (16,16) = 256 blocks (1/CU); 4 waves x R=64 rows: halves per-flop G
// traffic vs R=32 (the round-2 measured bottleneck). ROUND-3 FIX: no
// periodic __syncthreads (each drained the G-prefetch pipeline via
// vmcnt(0) with no co-resident block to cover the stall). G: even/odd
// register double-buffer, 1-lag-ahead prefetch (~310 MFMA cycles per lag
// covers the ~200-cycle L2 hit latency).
// ---------------------------------------------------------------------------
__global__ __launch_bounds__(256, 1) void conv_kernel(const float* __restrict__ x,
                                                      const u16* __restrict__ gsw,
                                                      float* __restrict__ y)
{
    __shared__ u16 Xs[XROWS * XSTR];   // 50,544 B

    const int tid = threadIdx.x;
    const int b  = blockIdx.y;
    const int t0 = blockIdx.x * CTILE;

    // Stage rows p=0..350 (= times t0-95 .. t0+255; t<0 -> zeros), converting.
    for (int u = tid; u < XROWS * 16; u += 256) {
        const int p = u >> 4, g = u & 15;
        const int t = t0 - (TLAG - 1) + p;
        ushort4 o;
        if (t < 0) { o.x = 0; o.y = 0; o.z = 0; o.w = 0; }
        else {
            const float4 v = *(const float4*)(x + ((size_t)b * SEQ + t) * 64 + g * 4);
            o.x = f2bf(v.x); o.y = f2bf(v.y); o.z = f2bf(v.z); o.w = f2bf(v.w);
        }
        *(ushort4*)&Xs[p * XSTR + g * 4] = o;
    }
    __syncthreads();

    const int w  = tid >> 6, l = tid & 63;
    const int lr = l & 15, q8 = (l >> 4) * 8;
    const int wrow = w * 64;

    const uint4* g4 = (const uint4*)gsw + l;

    f32x4 acc[4][4];
    const f32x4 zero = {0.f, 0.f, 0.f, 0.f};
    #pragma unroll
    for (int mt = 0; mt < 4; ++mt)
        #pragma unroll
        for (int nt = 0; nt < 4; ++nt) acc[mt][nt] = zero;

    uint4 bn0[8], bn1[8];
    #pragma unroll
    for (int f = 0; f < 8; ++f) bn0[f] = g4[f * 64];

    for (int m = 0; m < TLAG; m += 2) {
        {   // prefetch m+1 (always valid: TLAG even)
            const uint4* gp = g4 + (size_t)(m + 1) * 512;
            #pragma unroll
            for (int f = 0; f < 8; ++f) bn1[f] = gp[f * 64];
        }
        conv_step(Xs, bn0, wrow + lr + (TLAG - 1) - m, q8, acc);
        {   // prefetch m+2 (clamped; duplicate read is harmless)
            const int mp = (m + 2 < TLAG) ? (m + 2) : (TLAG - 1);
            const uint4* gp = g4 + (size_t)mp * 512;
            #pragma unroll
            for (int f = 0; f < 8; ++f) bn0[f] = gp[f * 64];
        }
        conv_step(Xs, bn1, wrow + lr + (TLAG - 1) - (m + 1), q8, acc);
    }

    // Epilogue: col=lane&15 (o), row=(lane>>4)*4+reg (time).
    const int rr = (l >> 4) * 4;
    #pragma unroll
    for (int mt = 0; mt < 4; ++mt) {
        #pragma unroll
        for (int nt = 0; nt < 4; ++nt) {
            const int t = t0 + wrow + mt * 16 + rr;
            const int o = nt * 16 + lr;
            float* yp = y + ((size_t)b * SEQ + t) * 64 + o;
            #pragma unroll
            for (int r = 0; r < 4; ++r) yp[(size_t)r * 64] = acc[mt][nt][r];
        }
    }
}

// ---------------------------------------------------------------------------
// Workspace layout (bytes):
//   0        bar      512   (grid-barrier cnt/gen; zeroed via hipMemsetAsync)
//   512      Ap0   524288   (A^h row-major, ping)
//   524800   Ap1   524288   (pong)
//   1049088  ApT0  524288   (A^h transposed, ping)
//   1573376  ApT1  524288   (pong)
//   2097664  BT     65536   (B^T [64][512])
//   2163200  Wall 6291456   ([96*64][512]: row m*64+o = (C A^m)[o][:])
//   8454656  Gsw   786432   (B-fragment-swizzled conv kernels, 96 lags)
//   total 9,241,088
// ---------------------------------------------------------------------------
extern "C" void kernel_launch(void* const* d_in, const int* in_sizes, int n_in,
                              void* d_out, int out_size, void* d_ws, size_t ws_size,
                              hipStream_t stream)
{
    const float* x = (const float*)d_in[0];
    const float* A = (const float*)d_in[1];
    const float* B = (const float*)d_in[2];
    const float* C = (const float*)d_in[3];
    const float* D = (const float*)d_in[4];
    float* y = (float*)d_out;

    char* w = (char*)d_ws;
    int* bar  = (int*)(w + 0);
    u16* Ap0  = (u16*)(w + 512);
    u16* Ap1  = (u16*)(w + 524800);
    u16* ApT0 = (u16*)(w + 1049088);
    u16* ApT1 = (u16*)(w + 1573376);
    u16* BT   = (u16*)(w + 2097664);
    u16* Wall = (u16*)(w + 2163200);
    u16* Gsw  = (u16*)(w + 8454656);

    hipMemsetAsync(bar, 0, 512, stream);
    precompute<<<256, 256, 0, stream>>>(A, B, C, D, Ap0, Ap1, ApT0, ApT1,
                                        BT, Wall, Gsw, bar);
    conv_kernel<<<dim3(SEQ / CTILE, BATCH), 256, 0, stream>>>(x, Gsw, y);
}